// Round 2
// baseline (696.308 us; speedup 1.0000x reference)
//
#include <hip/hip_runtime.h>

#define D 128

// ---------------- preprocessing kernels ----------------

__global__ void k_zero(int* __restrict__ p, int n) {
  int i = blockIdx.x * 256 + threadIdx.x;
  if (i < n) p[i] = 0;
}

__global__ void k_count(const int* __restrict__ dst, int* __restrict__ indeg, int E) {
  int e = blockIdx.x * 256 + threadIdx.x;
  if (e < E) atomicAdd(&indeg[dst[e]], 1);
}

// block-level exclusive scan (256/block), write local exclusive + block total
__global__ void k_scan1(const int* __restrict__ indeg, int* __restrict__ rp,
                        int* __restrict__ partials, int n) {
  __shared__ int s[256];
  int t = threadIdx.x;
  int i = blockIdx.x * 256 + t;
  int v = (i < n) ? indeg[i] : 0;
  s[t] = v;
  __syncthreads();
  for (int off = 1; off < 256; off <<= 1) {
    int x = (t >= off) ? s[t - off] : 0;
    __syncthreads();
    s[t] += x;
    __syncthreads();
  }
  if (i < n) rp[i] = s[t] - v;           // local exclusive
  if (t == 255) partials[blockIdx.x] = s[255];
}

// single-block exclusive scan of block partials (nb <= 512)
__global__ void k_scan2(int* __restrict__ partials, int nb) {
  __shared__ int s[512];
  int t = threadIdx.x;
  int v = (t < nb) ? partials[t] : 0;
  s[t] = v;
  __syncthreads();
  for (int off = 1; off < 512; off <<= 1) {
    int x = (t >= off) ? s[t - off] : 0;
    __syncthreads();
    s[t] += x;
    __syncthreads();
  }
  if (t < nb) partials[t] = s[t] - v;    // exclusive
}

// add block offsets; init fill counters; compute dinv = rsqrt(indeg+1)
__global__ void k_scan3(const int* __restrict__ indeg, int* __restrict__ rp,
                        const int* __restrict__ partials, int* __restrict__ fillp,
                        float* __restrict__ dinv, int n) {
  int i = blockIdx.x * 256 + threadIdx.x;
  if (i < n) {
    int v = rp[i] + partials[blockIdx.x];
    rp[i] = v;
    fillp[i] = v;
    dinv[i] = rsqrtf((float)(indeg[i] + 1));
  }
}

// counting-sort edges by dst: csr[pos] = src
__global__ void k_fill(const int* __restrict__ src, const int* __restrict__ dst,
                       int* __restrict__ fillp, int* __restrict__ csr, int E) {
  int e = blockIdx.x * 256 + threadIdx.x;
  if (e < E) {
    int pos = atomicAdd(&fillp[dst[e]], 1);
    csr[pos] = src[e];
  }
}

// ---------------- GEMM: out[row] = dinv[row] * (X[gather(row)] @ W) ----------------
// 64 rows x 64 cols per block, 256 threads, 4x4 register blocking.
// LDS: Xs 64x128 (32KB) + Ws 128x64 (32KB) = 64KB -> 2 blocks/CU.

#define F4E(v, j) ((j) == 0 ? (v).x : ((j) == 1 ? (v).y : ((j) == 2 ? (v).z : (v).w)))

__global__ __launch_bounds__(256) void k_gemm(const float* __restrict__ X,
                                              const int* __restrict__ xidx,
                                              const float* __restrict__ W,
                                              const float* __restrict__ dinv,
                                              float* __restrict__ out, int n) {
  __shared__ float Xs[64 * D];   // 32 KB
  __shared__ float Ws[D * 64];   // 32 KB
  int tid = threadIdx.x;
  int r0 = blockIdx.x * 64;
  int c0 = blockIdx.y * 64;

  // stage W[:, c0..c0+63]  (rows of 16 float4)
  {
    const float4* W4 = (const float4*)W;
    float4* Ws4 = (float4*)Ws;
    for (int i = tid; i < 128 * 16; i += 256) {
      int k = i >> 4, cc = i & 15;
      Ws4[i] = W4[k * (D / 4) + (c0 >> 2) + cc];
    }
  }
  // stage X rows r0..r0+63 (optional gather through xidx)
  {
    float4* Xs4 = (float4*)Xs;
    const float4* X4 = (const float4*)X;
    for (int i = tid; i < 64 * 32; i += 256) {
      int r = i >> 5, kc = i & 31;
      int row = r0 + r;
      float4 v = make_float4(0.f, 0.f, 0.f, 0.f);
      if (row < n) {
        int srow = xidx ? xidx[row] : row;
        v = X4[srow * 32 + kc];
      }
      Xs4[i] = v;
    }
  }
  __syncthreads();

  int cg = (tid & 15) * 4;    // col within tile
  int rg = (tid >> 4) * 4;    // row within tile
  float acc[4][4] = {{0.f}};
  const float4* Xs4 = (const float4*)Xs;
  const float4* Ws4 = (const float4*)Ws;

#pragma unroll 4
  for (int k4 = 0; k4 < D; k4 += 4) {
    float4 a[4], w[4];
#pragma unroll
    for (int i = 0; i < 4; i++) a[i] = Xs4[((rg + i) * D + k4) >> 2];
#pragma unroll
    for (int kk = 0; kk < 4; kk++) w[kk] = Ws4[((k4 + kk) * 64 + cg) >> 2];
#pragma unroll
    for (int kk = 0; kk < 4; kk++)
#pragma unroll
      for (int i = 0; i < 4; i++)
#pragma unroll
        for (int j = 0; j < 4; j++)
          acc[i][j] += F4E(a[i], kk) * F4E(w[kk], j);
  }

#pragma unroll
  for (int i = 0; i < 4; i++) {
    int row = r0 + rg + i;
    if (row < n) {
      float sc = dinv[row];
      float4 o = make_float4(acc[i][0] * sc, acc[i][1] * sc,
                             acc[i][2] * sc, acc[i][3] * sc);
      ((float4*)out)[(row * D + c0 + cg) >> 2] = o;
    }
  }
}

// ---------------- aggregation: out[d] = act(dinv[d]*(sum_{s->d} hs[s] + hs[d]) + b) ----
// one 32-lane group per node; lane owns 4 consecutive cols (float4).
// Neighbor loop unrolled 4x: 4 independent index reads -> 4 independent
// float4 gathers in flight per iteration (latency-bound fix).

__global__ __launch_bounds__(256) void k_agg(const float* __restrict__ hs,
                                             const int* __restrict__ rp,
                                             const int* __restrict__ indeg,
                                             const int* __restrict__ csr,
                                             const float* __restrict__ dinv,
                                             const float* __restrict__ bias,
                                             float* __restrict__ out, int n, int relu) {
  int lane = threadIdx.x & 31;
  int d = (blockIdx.x * 256 + threadIdx.x) >> 5;
  if (d >= n) return;
  const float4* hs4 = (const float4*)hs;
  float4 acc = hs4[d * 32 + lane];     // self-loop term (hs = dinv*h)
  int start = rp[d];
  int cnt = indeg[d];
  const int* nb = csr + start;

  int e = 0;
  for (; e + 4 <= cnt; e += 4) {
    int s0 = nb[e], s1 = nb[e + 1], s2 = nb[e + 2], s3 = nb[e + 3];
    float4 v0 = hs4[s0 * 32 + lane];
    float4 v1 = hs4[s1 * 32 + lane];
    float4 v2 = hs4[s2 * 32 + lane];
    float4 v3 = hs4[s3 * 32 + lane];
    acc.x += v0.x + v1.x + v2.x + v3.x;
    acc.y += v0.y + v1.y + v2.y + v3.y;
    acc.z += v0.z + v1.z + v2.z + v3.z;
    acc.w += v0.w + v1.w + v2.w + v3.w;
  }
  for (; e < cnt; e++) {
    float4 v = hs4[nb[e] * 32 + lane];
    acc.x += v.x; acc.y += v.y; acc.z += v.z; acc.w += v.w;
  }

  float sc = dinv[d];
  float4 bv = ((const float4*)bias)[lane];
  float4 o;
  o.x = sc * acc.x + bv.x;
  o.y = sc * acc.y + bv.y;
  o.z = sc * acc.z + bv.z;
  o.w = sc * acc.w + bv.w;
  if (relu) {
    o.x = fmaxf(o.x, 0.f); o.y = fmaxf(o.y, 0.f);
    o.z = fmaxf(o.z, 0.f); o.w = fmaxf(o.w, 0.f);
  }
  ((float4*)out)[d * 32 + lane] = o;
}

// ---------------- launcher ----------------

extern "C" void kernel_launch(void* const* d_in, const int* in_sizes, int n_in,
                              void* d_out, int out_size, void* d_ws, size_t ws_size,
                              hipStream_t stream) {
  const int* x_idx = (const int*)d_in[0];
  const int* eidx  = (const int*)d_in[1];
  const float* emb = (const float*)d_in[2];
  const float* W1  = (const float*)d_in[3];
  const float* b1  = (const float*)d_in[4];
  const float* W2  = (const float*)d_in[5];
  const float* b2  = (const float*)d_in[6];
  float* outp = (float*)d_out;

  int n = in_sizes[0];
  int E = in_sizes[1] / 2;
  const int* src = eidx;
  const int* dst = eidx + E;

  // workspace carve (16B aligned)
  char* w = (char*)d_ws;
  auto carve = [&](size_t bytes) {
    void* p = (void*)w;
    w += (bytes + 15) & ~size_t(15);
    return p;
  };
  int*   indeg    = (int*)carve((size_t)n * 4);
  int*   rp       = (int*)carve((size_t)n * 4);
  int*   fillp    = (int*)carve((size_t)n * 4);
  float* dinv     = (float*)carve((size_t)n * 4);
  int*   partials = (int*)carve(512 * 4);
  int*   csr      = (int*)carve((size_t)E * 4);
  float* buf1     = (float*)carve((size_t)n * D * 4);
  float* buf2     = (float*)carve((size_t)n * D * 4);

  int nb = (n + 255) / 256;   // 391 <= 512

  k_zero<<<nb, 256, 0, stream>>>(indeg, n);
  k_count<<<(E + 255) / 256, 256, 0, stream>>>(dst, indeg, E);
  k_scan1<<<nb, 256, 0, stream>>>(indeg, rp, partials, n);
  k_scan2<<<1, 512, 0, stream>>>(partials, nb);
  k_scan3<<<nb, 256, 0, stream>>>(indeg, rp, partials, fillp, dinv, n);
  k_fill<<<(E + 255) / 256, 256, 0, stream>>>(src, dst, fillp, csr, E);

  dim3 gemm_grid((n + 63) / 64, D / 64);
  int agg_blocks = (n * 32 + 255) / 256;

  // layer 1: hs1 = dinv * (emb[x_idx] @ W1); out1 = relu(dinv*(agg)+b1)
  k_gemm<<<gemm_grid, 256, 0, stream>>>(emb, x_idx, W1, dinv, buf1, n);
  k_agg<<<agg_blocks, 256, 0, stream>>>(buf1, rp, indeg, csr, dinv, b1, buf2, n, 1);
  // layer 2
  k_gemm<<<gemm_grid, 256, 0, stream>>>(buf2, nullptr, W2, dinv, buf1, n);
  k_agg<<<agg_blocks, 256, 0, stream>>>(buf1, rp, indeg, csr, dinv, b2, outp, n, 0);
}